// Round 1
// baseline (557.495 us; speedup 1.0000x reference)
//
#include <hip/hip_runtime.h>

typedef _Float16 f16;
typedef __attribute__((ext_vector_type(4))) _Float16 f16x4;
typedef __attribute__((ext_vector_type(8))) _Float16 f16x8;
typedef __attribute__((ext_vector_type(4))) float f32x4;

#define DEVI static __device__ __forceinline__

DEVI void async_copy16(const f16* g, f16* l) {
  __builtin_amdgcn_global_load_lds(
      (const __attribute__((address_space(1))) void*)g,
      (__attribute__((address_space(3))) void*)l, 16, 0, 0);
}

// ---------------- adjacency: build normalized A, A2=A@A, rowsum(A2) ----------------
__global__ __launch_bounds__(1024) void k_adj(const float* __restrict__ ew, float* __restrict__ out)
{
  __shared__ float sW[62][64];
  __shared__ float sT[62][64];
  __shared__ float d[62];
  const int tid = threadIdx.x;
  for (int idx = tid; idx < 62 * 62; idx += 1024) {
    int i = idx / 62, j = idx % 62;
    float w = (j <= i) ? ew[i * (i + 1) / 2 + j] : ew[j * (j + 1) / 2 + i];
    sW[i][j] = fmaxf(w, 0.f);
  }
  __syncthreads();
  if (tid < 62) {
    float s = 0.f;
    for (int j = 0; j < 62; j++) s += sW[tid][j];
    d[tid] = rsqrtf(s + 1e-10f);
  }
  __syncthreads();
  for (int idx = tid; idx < 62 * 62; idx += 1024) {
    int i = idx / 62, j = idx % 62;
    sW[i][j] *= d[i] * d[j];
  }
  __syncthreads();
  if (tid < 62) {
    float s = 0.f;
    for (int j = 0; j < 62; j++) s += sW[tid][j];
    d[tid] = (s > 0.f) ? rsqrtf(s) : 0.f;
  }
  __syncthreads();
  for (int idx = tid; idx < 62 * 62; idx += 1024) {
    int i = idx / 62, j = idx % 62;
    sW[i][j] *= d[i] * d[j];
  }
  __syncthreads();
  for (int idx = tid; idx < 62 * 64; idx += 1024) {
    int i = idx >> 6, j = idx & 63;
    float s = 0.f;
    if (j < 62) {
      for (int k = 0; k < 62; k++) s += sW[i][k] * sW[k][j];
    }
    sT[i][j] = s;
    out[idx] = s;
  }
  __syncthreads();
  if (tid < 62) {
    float s = 0.f;
    for (int j = 0; j < 62; j++) s += sT[tid][j];
    out[62 * 64 + tid] = s;   // rowsum(A2)
  }
}

// ---------------- BN stats: per-block partial sums (deterministic) ----------------
__global__ __launch_bounds__(256) void k_bnstats(const float* __restrict__ X, float* __restrict__ part)
{
  const int tid = threadIdx.x;
  const int c4 = (tid & 127) << 2;
  const int hf = tid >> 7;
  float sx = 0, sy = 0, sz = 0, sw = 0, qx = 0, qy = 0, qz = 0, qw = 0;
  const long r0 = (long)blockIdx.x * 496 + hf;
  for (int i = 0; i < 248; i++) {
    const float4 v = *(const float4*)(X + (r0 + 2 * i) * 512 + c4);
    sx += v.x; sy += v.y; sz += v.z; sw += v.w;
    qx += v.x * v.x; qy += v.y * v.y; qz += v.z * v.z; qw += v.w * v.w;
  }
  __shared__ float red[256][8];
  red[tid][0] = sx; red[tid][1] = sy; red[tid][2] = sz; red[tid][3] = sw;
  red[tid][4] = qx; red[tid][5] = qy; red[tid][6] = qz; red[tid][7] = qw;
  __syncthreads();
  if (tid < 128) {
    float* p = part + (long)blockIdx.x * 1024;
#pragma unroll
    for (int j = 0; j < 4; j++) p[c4 + j] = red[tid][j] + red[tid + 128][j];
#pragma unroll
    for (int j = 0; j < 4; j++) p[512 + c4 + j] = red[tid][4 + j] + red[tid + 128][4 + j];
  }
}

__global__ __launch_bounds__(512) void k_bnfin(const float* __restrict__ part, const float* __restrict__ g,
                                               const float* __restrict__ be, float* __restrict__ ssb)
{
  const int c = threadIdx.x;  // 512
  float s = 0.f, q = 0.f;
  for (int b = 0; b < 256; b++) {
    s += part[b * 1024 + c];
    q += part[b * 1024 + 512 + c];
  }
  const float inv = 1.f / 126976.f;
  const float mean = s * inv;
  const float var = q * inv - mean * mean;
  const float sc = g[c] * rsqrtf(var + 1e-5f);
  ssb[c] = sc;
  ssb[512 + c] = be[c] - mean * sc;
}

// ---------------- fold BN scale into lin_w; b1p[h] = sum_f t[f]*W[h][f] ----------------
__global__ __launch_bounds__(256) void k_foldw1(const float* __restrict__ lw, const float* __restrict__ ssb,
                                                f16* __restrict__ w1h, float* __restrict__ b1p)
{
  const int h = blockIdx.x;
  const int tid = threadIdx.x;
  float partl = 0.f;
  for (int f = tid; f < 512; f += 256) {
    const float w = lw[h * 512 + f];
    w1h[h * 512 + f] = (f16)(w * ssb[f]);
    partl += w * ssb[512 + f];
  }
  __shared__ float red[256];
  red[tid] = partl;
  __syncthreads();
  for (int s = 128; s; s >>= 1) {
    if (tid < s) red[tid] += red[tid + s];
    __syncthreads();
  }
  if (tid == 0) b1p[h] = red[0];
}

// ---------------- fp32 -> fp16 weight convert with N/K zero-padding ----------------
__global__ __launch_bounds__(256) void k_cvtw(const float* __restrict__ src, f16* __restrict__ dst,
                                              int N, int K, int Npad, int Kpad)
{
  const long total4 = (long)Npad * Kpad / 4;
  const int kp4 = Kpad >> 2;
  for (long i = (long)blockIdx.x * 256 + threadIdx.x; i < total4; i += (long)gridDim.x * 256) {
    const long n = i / kp4;
    const int k = (int)(i % kp4) << 2;
    f16x4 h;
    if (n < N && k < K) {
      const float4 v = *(const float4*)(src + n * K + k);
      h[0] = (f16)v.x; h[1] = (f16)v.y; h[2] = (f16)v.z; h[3] = (f16)v.w;
    } else {
      h[0] = (f16)0.f; h[1] = (f16)0.f; h[2] = (f16)0.f; h[3] = (f16)0.f;
    }
    *(f16x4*)(dst + i * 4) = h;
  }
}

// ---------------- GEMM1: Y[M=126976,128] = (x) @ w1h^T (scale pre-folded) ----------------
__global__ __launch_bounds__(256, 2) void k_gemm_lin(
    const float* __restrict__ X, const f16* __restrict__ Bw, f16* __restrict__ Y)
{
  __shared__ f16 sA[128 * 64];
  __shared__ f16 sB[128 * 64];
  const int tid = threadIdx.x;
  const int lane = tid & 63;
  const int wave = tid >> 6;
  const int wr = wave >> 1, wc = wave & 1;
  const long rowA0 = (long)blockIdx.x * 128;

  const int srow = tid >> 3;
  const int scolb = (tid & 7) << 4;
  const int gcolb = scolb ^ ((srow & 7) << 4);
  const f16* gB = Bw + (long)srow * 512 + (gcolb >> 1);
  f16* lB = sB + srow * 64 + (scolb >> 1);

  const int ac4 = tid & 15;
  const int ar0 = tid >> 4;
  const int aswz = (ar0 & 7) << 4;
  const float* gX = X + (rowA0 + ar0) * 512 + ac4 * 4;
  char* lAbase = (char*)sA + ar0 * 128 + ((ac4 * 8) ^ aswz);

  const int frow = lane & 15;
  const int kb = (lane >> 4) << 4;
  const int rswz = (lane & 7) << 4;

  f32x4 acc[4][4] = {};

  for (int kt = 0; kt < 512; kt += 64) {
#pragma unroll
    for (int i = 0; i < 8; i++) {
      const float4 v = *(const float4*)(gX + kt + (long)(16 * i) * 512);
      f16x4 hh;
      hh[0] = (f16)v.x; hh[1] = (f16)v.y; hh[2] = (f16)v.z; hh[3] = (f16)v.w;
      *(f16x4*)(lAbase + 16 * i * 128) = hh;
    }
#pragma unroll
    for (int i = 0; i < 4; i++)
      async_copy16(gB + kt + (long)i * (32 * 512), lB + i * 2048);
    __syncthreads();
#pragma unroll
    for (int kk = 0; kk < 2; kk++) {
      f16x8 af[4], bf[4];
#pragma unroll
      for (int m = 0; m < 4; m++) {
        const int row = wr * 64 + m * 16 + frow;
        af[m] = *(const f16x8*)((const char*)sA + row * 128 + ((kk * 64 + kb) ^ rswz));
      }
#pragma unroll
      for (int n = 0; n < 4; n++) {
        const int row = wc * 64 + n * 16 + frow;
        bf[n] = *(const f16x8*)((const char*)sB + row * 128 + ((kk * 64 + kb) ^ rswz));
      }
#pragma unroll
      for (int m = 0; m < 4; m++)
#pragma unroll
        for (int n = 0; n < 4; n++)
          acc[m][n] = __builtin_amdgcn_mfma_f32_16x16x32_f16(af[m], bf[n], acc[m][n], 0, 0, 0);
    }
    __syncthreads();
  }

  const int crow = wr * 64 + ((lane >> 4) << 2);
  const int ccol = wc * 64 + (lane & 15);
#pragma unroll
  for (int n = 0; n < 4; n++) {
    const int col = ccol + n * 16;
#pragma unroll
    for (int m = 0; m < 4; m++) {
      const long gr = rowA0 + crow + m * 16;
#pragma unroll
      for (int r = 0; r < 4; r++)
        Y[(gr + r) * 128 + col] = (f16)acc[m][n][r];
    }
  }
}

// ---------------- propagation: Z[b] = A2 @ Y[b] + rowsum(A2)*b1p + lin_b ----------------
__global__ __launch_bounds__(256) void k_prop(const f16* __restrict__ Y, const float* __restrict__ A2,
                                              const float* __restrict__ b1p, const float* __restrict__ lb,
                                              f16* __restrict__ Z)
{
  __shared__ float sY[62 * 128];
  __shared__ float sA[62 * 64];
  __shared__ float sR[62];
  __shared__ float sB1[128];
  __shared__ float sLB[128];
  const int tid = threadIdx.x;
  const long base = (long)blockIdx.x * 7936;
  for (int i = tid; i < 992; i += 256) {
    const f16x8 v = *(const f16x8*)(Y + base + (long)i * 8);
#pragma unroll
    for (int j = 0; j < 8; j++) sY[i * 8 + j] = (float)v[j];
    const float4 a = *(const float4*)(A2 + i * 4);
    *(float4*)&sA[i * 4] = a;
  }
  if (tid < 62) sR[tid] = A2[3968 + tid];
  if (tid >= 64 && tid < 192) sB1[tid - 64] = b1p[tid - 64];
  if (tid >= 128 && tid < 256) sLB[tid - 128] = lb[tid - 128];
  __syncthreads();
  const int h = tid & 127;
  const int ng = tid >> 7;
  float yc[62];
#pragma unroll
  for (int j = 0; j < 62; j++) yc[j] = sY[j * 128 + h];
  const float bias_h1 = sB1[h];
  const float bias_h2 = sLB[h];
  for (int n = ng; n < 62; n += 2) {
    float s = 0.f;
#pragma unroll
    for (int j = 0; j < 62; j++) s += sA[n * 64 + j] * yc[j];
    s += sR[n] * bias_h1 + bias_h2;
    Z[base + n * 128 + h] = (f16)s;
  }
}

// ---------------- generic fp16 BT GEMM: C = act(A[2048,K] @ B[N,K]^T + bias) ----------------
template <int RELU>
__global__ __launch_bounds__(256, 2) void k_gemm_f16(
    const f16* __restrict__ A, const f16* __restrict__ B,
    const float* __restrict__ bias, f16* __restrict__ C,
    int N, int K, int realN)
{
  __shared__ f16 sA[128 * 64];
  __shared__ f16 sB[128 * 64];
  const int tid = threadIdx.x;
  const int lane = tid & 63;
  const int wave = tid >> 6;
  const int wr = wave >> 1, wc = wave & 1;
  const long rowA0 = (long)blockIdx.y * 128;
  const long rowB0 = (long)blockIdx.x * 128;

  const int srow = tid >> 3;
  const int scolb = (tid & 7) << 4;
  const int gcolb = scolb ^ ((srow & 7) << 4);
  const f16* gA = A + (rowA0 + srow) * (long)K + (gcolb >> 1);
  const f16* gB = B + (rowB0 + srow) * (long)K + (gcolb >> 1);
  f16* lA = sA + srow * 64 + (scolb >> 1);
  f16* lB = sB + srow * 64 + (scolb >> 1);
  const long rstep = 32L * K;

  const int frow = lane & 15;
  const int kb = (lane >> 4) << 4;
  const int rswz = (lane & 7) << 4;

  f32x4 acc[4][4] = {};

  for (int kt = 0; kt < K; kt += 64) {
#pragma unroll
    for (int i = 0; i < 4; i++) {
      async_copy16(gA + kt + i * rstep, lA + i * 2048);
      async_copy16(gB + kt + i * rstep, lB + i * 2048);
    }
    __syncthreads();
#pragma unroll
    for (int kk = 0; kk < 2; kk++) {
      f16x8 af[4], bf[4];
#pragma unroll
      for (int m = 0; m < 4; m++) {
        const int row = wr * 64 + m * 16 + frow;
        af[m] = *(const f16x8*)((const char*)sA + row * 128 + ((kk * 64 + kb) ^ rswz));
      }
#pragma unroll
      for (int n = 0; n < 4; n++) {
        const int row = wc * 64 + n * 16 + frow;
        bf[n] = *(const f16x8*)((const char*)sB + row * 128 + ((kk * 64 + kb) ^ rswz));
      }
#pragma unroll
      for (int m = 0; m < 4; m++)
#pragma unroll
        for (int n = 0; n < 4; n++)
          acc[m][n] = __builtin_amdgcn_mfma_f32_16x16x32_f16(af[m], bf[n], acc[m][n], 0, 0, 0);
    }
    __syncthreads();
  }

  const int crow = wr * 64 + ((lane >> 4) << 2);
  const int ccol = wc * 64 + (lane & 15);
#pragma unroll
  for (int n = 0; n < 4; n++) {
    const int col = (int)rowB0 + ccol + n * 16;
    const float bb = (col < realN) ? bias[col] : 0.f;
#pragma unroll
    for (int m = 0; m < 4; m++) {
      const long gr = rowA0 + crow + m * 16;
#pragma unroll
      for (int r = 0; r < 4; r++) {
        float v = acc[m][n][r] + bb;
        if (RELU) v = fmaxf(v, 0.f);
        C[(gr + r) * N + col] = (f16)v;
      }
    }
  }
}

// ---------------- fc3: out[2048,2] = h2[:, :992] @ w3^T + b3 ----------------
__global__ __launch_bounds__(256) void k_fc3(const f16* __restrict__ H, const float* __restrict__ W,
                                             const float* __restrict__ b, float* __restrict__ out)
{
  const int row = blockIdx.x * 4 + (threadIdx.x >> 6);
  const int lane = threadIdx.x & 63;
  const f16* h = H + (long)row * 1024;
  float a0 = 0.f, a1 = 0.f;
  for (int k = lane; k < 992; k += 64) {
    const float v = (float)h[k];
    a0 += v * W[k];
    a1 += v * W[992 + k];
  }
  for (int off = 32; off; off >>= 1) {
    a0 += __shfl_down(a0, off);
    a1 += __shfl_down(a1, off);
  }
  if (lane == 0) {
    out[row * 2 + 0] = a0 + b[0];
    out[row * 2 + 1] = a1 + b[1];
  }
}

extern "C" void kernel_launch(void* const* d_in, const int* in_sizes, int n_in,
                              void* d_out, int out_size, void* d_ws, size_t ws_size,
                              hipStream_t stream)
{
  const float* x    = (const float*)d_in[0];
  const float* ew   = (const float*)d_in[1];
  const float* bng  = (const float*)d_in[2];
  const float* bnb  = (const float*)d_in[3];
  const float* linw = (const float*)d_in[4];
  const float* linb = (const float*)d_in[5];
  const float* w0   = (const float*)d_in[6];
  const float* b0   = (const float*)d_in[7];
  const float* w1   = (const float*)d_in[8];
  const float* b1   = (const float*)d_in[9];
  const float* w2   = (const float*)d_in[10];
  const float* b2   = (const float*)d_in[11];
  const float* w3   = (const float*)d_in[12];
  const float* b3   = (const float*)d_in[13];
  float* out = (float*)d_out;
  char* ws = (char*)d_ws;

  constexpr size_t oA2  = 0;                       // 62*64 + 62 floats
  constexpr size_t oACC = 16384;                   // 256*1024 floats
  constexpr size_t oSS  = oACC + 1048576;          // 1024 floats (scale,shift)
  constexpr size_t oB1P = oSS + 4096;              // 128 floats
  constexpr size_t oW1H = oB1P + 512;              // 128*512 f16
  constexpr size_t oY   = oW1H + 131072;           // 126976*128 f16 (reused by h0/h1/h2)
  constexpr size_t oH0  = oY;                      // 2048*3968 f16
  constexpr size_t oH1  = oH0 + 16252928;          // 2048*2048 f16
  constexpr size_t oH2  = oH1 + 8388608;           // 2048*1024 f16
  constexpr size_t oZ   = oY + 32505856;           // 2048*7936 f16
  constexpr size_t oW0H = oZ + 32505856;           // 3968*7936 f16
  constexpr size_t oW1F = oW0H + 62980096;         // 2048*3968 f16
  constexpr size_t oW2F = oW1F + 16252928;         // 1024*2048 f16
  constexpr size_t WS_NEED = oW2F + 4194304;
  if (ws_size < WS_NEED) return;  // fail loudly via wrong output

  float* A2  = (float*)(ws + oA2);
  float* acc = (float*)(ws + oACC);
  float* ssb = (float*)(ws + oSS);
  float* b1p = (float*)(ws + oB1P);
  f16* w1h = (f16*)(ws + oW1H);
  f16* Y   = (f16*)(ws + oY);
  f16* h0  = (f16*)(ws + oH0);
  f16* h1  = (f16*)(ws + oH1);
  f16* h2  = (f16*)(ws + oH2);
  f16* Z   = (f16*)(ws + oZ);
  f16* w0h = (f16*)(ws + oW0H);
  f16* w1f = (f16*)(ws + oW1F);
  f16* w2f = (f16*)(ws + oW2F);

  k_adj<<<1, 1024, 0, stream>>>(ew, A2);
  k_bnstats<<<256, 256, 0, stream>>>(x, acc);
  k_bnfin<<<1, 512, 0, stream>>>(acc, bng, bnb, ssb);
  k_foldw1<<<128, 256, 0, stream>>>(linw, ssb, w1h, b1p);
  k_cvtw<<<1024, 256, 0, stream>>>(w0, w0h, 3968, 7936, 3968, 7936);
  k_cvtw<<<1024, 256, 0, stream>>>(w1, w1f, 1984, 3968, 2048, 3968);
  k_cvtw<<<1024, 256, 0, stream>>>(w2, w2f, 992, 1984, 1024, 2048);
  k_gemm_lin<<<992, 256, 0, stream>>>(x, w1h, Y);
  k_prop<<<2048, 256, 0, stream>>>(Y, A2, b1p, linb, Z);
  k_gemm_f16<1><<<dim3(31, 16), 256, 0, stream>>>(Z, w0h, b0, h0, 3968, 7936, 3968);
  k_gemm_f16<1><<<dim3(16, 16), 256, 0, stream>>>(h0, w1f, b1, h1, 2048, 3968, 1984);
  k_gemm_f16<1><<<dim3(8, 16), 256, 0, stream>>>(h1, w2f, b2, h2, 1024, 2048, 992);
  k_fc3<<<512, 256, 0, stream>>>(h2, w3, b3, out);
}